// Round 3
// baseline (137.071 us; speedup 1.0000x reference)
//
#include <hip/hip_runtime.h>
#include <hip/hip_bf16.h>

#define B_BATCH 512
#define NPB     500
#define DIM     128
#define VOCAB   50000
#define MAXD    40
#define NPREP   512
#define NGEMM   ((VOCAB + 63) / 64)   // 782

typedef short bf16x8 __attribute__((ext_vector_type(8)));
typedef float f32x4  __attribute__((ext_vector_type(4)));

__device__ __forceinline__ unsigned short f2bf(float x) {
    unsigned u = __float_as_uint(x);
    return (unsigned short)((u + 0x7fffu + ((u >> 16) & 1u)) >> 16);   // RTNE
}

// Prep-branch LDS overlaid with the GEMM branch's 32 KB WcT4 buffer so the
// kernel's static LDS is max(32K, 14.5K) = 32 KB, not the sum (keeps 4 blk/CU).
struct PrepShm {
    int   tokL[NPB];
    int   sizeL[NPB];
    int   childCur[NPB];
    int   tmpTok[NPB];
    int   hist[MAXD + 1], off[MAXD + 1], cur[MAXD + 1];
    int   sdmax;
    unsigned short parL[NPB];
    unsigned short depL[NPB];
    unsigned short sibp[NPB];
    unsigned short tinL[NPB];
    unsigned short bucket[NPB];
    unsigned short tmpEnd[NPB];
};

// ---------- fused prep (blocks 0..511) + MFMA gemm (blocks 512..1293) ----------
__global__ __launch_bounds__(256) void prep_gemm(const int* __restrict__ tokens,
                                                 const int* __restrict__ parent,
                                                 const int* __restrict__ depth,
                                                 const float* __restrict__ emb,
                                                 const float* __restrict__ Wc,
                                                 const float* __restrict__ bc,
                                                 int* __restrict__ tokD,
                                                 unsigned short* __restrict__ endD,
                                                 unsigned short* __restrict__ Eb) {
    __shared__ __align__(16) unsigned char shm[32768];
    const int tid = threadIdx.x;

    if (blockIdx.x >= NPREP) {
        // ================= GEMM branch =================
        // All 4 kc-stages of Wc staged into WcT4[4][128][32] with ONE barrier
        // (stages write disjoint LDS; nothing reads before the sync). emb
        // loads hoisted ahead of staging so HBM latency hides under the
        // Wc convert/write VALU work. Inner layout identical to prior rounds.
        unsigned short* WcT4 = (unsigned short*)shm;     // 32 KB

        const int lane = tid & 63, w = tid >> 6;
        const int q = lane >> 4, mc = lane & 15;
        const int rowBase = (blockIdx.x - NPREP) * 64;
        const int arow = min(rowBase + w * 16 + mc, VOCAB - 1);   // clamp, no OOB

        // ---- A: issue all 8 emb loads up-front ----
        const float* esrc = &emb[(long long)arow * DIM];
        float4 ev[8];
        #pragma unroll
        for (int kc = 0; kc < 4; ++kc) {
            const float* src = esrc + kc * 32 + q * 8;
            ev[2 * kc]     = *(const float4*)src;
            ev[2 * kc + 1] = *(const float4*)(src + 4);
        }

        // ---- stage all of Wc (bf16, transposed) ----
        const int kk = tid >> 3;           // 0..31 : k within stage
        const int c0 = (tid & 7) * 16;     // col base, 16 cols per thread
        #pragma unroll
        for (int s = 0; s < 4; ++s) {
            const float* wsrc = &Wc[(s * 32 + kk) * DIM + c0];
            float wv[16];
            *(float4*)(wv + 0)  = *(const float4*)(wsrc + 0);
            *(float4*)(wv + 4)  = *(const float4*)(wsrc + 4);
            *(float4*)(wv + 8)  = *(const float4*)(wsrc + 8);
            *(float4*)(wv + 12) = *(const float4*)(wsrc + 12);
            #pragma unroll
            for (int i = 0; i < 16; ++i)
                WcT4[s * 4096 + (c0 + i) * 32 + kk] = f2bf(wv[i]);
        }

        // ---- convert A fragments while staging stores drain ----
        bf16x8 a4[4];
        #pragma unroll
        for (int kc = 0; kc < 4; ++kc) {
            float4 v0 = ev[2 * kc], v1 = ev[2 * kc + 1];
            unsigned short aw[8] = {f2bf(v0.x), f2bf(v0.y), f2bf(v0.z), f2bf(v0.w),
                                    f2bf(v1.x), f2bf(v1.y), f2bf(v1.z), f2bf(v1.w)};
            a4[kc] = *(bf16x8*)aw;
        }
        __syncthreads();   // the ONLY barrier in the GEMM branch

        f32x4 acc[8];
        #pragma unroll
        for (int nt = 0; nt < 8; ++nt) acc[nt] = (f32x4){0.f, 0.f, 0.f, 0.f};

        #pragma unroll
        for (int kc = 0; kc < 4; ++kc) {
            #pragma unroll
            for (int nt = 0; nt < 8; ++nt) {
                bf16x8 bfr = *(bf16x8*)&WcT4[kc * 4096 + (nt * 16 + mc) * 32 + q * 8];
                acc[nt] = __builtin_amdgcn_mfma_f32_16x16x32_bf16(a4[kc], bfr, acc[nt], 0, 0, 0);
            }
        }

        #pragma unroll
        for (int nt = 0; nt < 8; ++nt) {
            float bcv = bc[nt * 16 + mc];
            #pragma unroll
            for (int r = 0; r < 4; ++r) {
                int grow = rowBase + w * 16 + q * 4 + r;
                if (grow < VOCAB)
                    Eb[(long long)grow * DIM + nt * 16 + mc] = f2bf(acc[nt][r] + bcv);
            }
        }
        return;
    }

    // ================= PREP branch =================
    PrepShm& P = *(PrepShm*)shm;

    const int b = blockIdx.x;
    const long long base = (long long)b * NPB;

    if (tid <= MAXD) P.hist[tid] = 0;
    __syncthreads();
    for (int n = tid; n < NPB; n += 256) {
        int d = depth[base + n];
        P.depL[n]  = (unsigned short)d;
        P.parL[n]  = (unsigned short)(n == 0 ? 0 : (int)(parent[base + n] - base));
        P.tokL[n]  = tokens[base + n];
        P.sizeL[n] = 1;
        P.childCur[n] = 0;
        if (n > 0) atomicAdd(&P.hist[d], 1);
    }
    __syncthreads();

    if (tid < 64) {
        int h = (tid >= 1 && tid <= MAXD) ? P.hist[tid] : 0;
        int x = h;
        #pragma unroll
        for (int o = 1; o < 64; o <<= 1) { int y = __shfl_up(x, o, 64); if (tid >= o) x += y; }
        if (tid >= 1 && tid <= MAXD) { P.off[tid] = x - h; P.cur[tid] = x - h; }
        int dm = (h > 0) ? tid : 0;
        #pragma unroll
        for (int o = 32; o; o >>= 1) dm = max(dm, __shfl_down(dm, o));
        if (tid == 0) P.sdmax = dm;
    }
    __syncthreads();

    for (int n = 1 + tid; n < NPB; n += 256)
        P.bucket[atomicAdd(&P.cur[P.depL[n]], 1)] = (unsigned short)n;
    __syncthreads();
    const int dmax = P.sdmax;

    // bottom-up subtree sizes (depth-ordered, atomics within a level)
    for (int d = dmax; d >= 1; --d) {
        int c = P.hist[d], o = P.off[d];
        for (int i = tid; i < c; i += 256) {
            int n = P.bucket[o + i];
            atomicAdd(&P.sizeL[P.parL[n]], P.sizeL[n]);
        }
        __syncthreads();
    }

    // sibling offsets: exclusive prefix of sizes in atomic arrival order
    for (int n = 1 + tid; n < NPB; n += 256)
        P.sibp[n] = (unsigned short)atomicAdd(&P.childCur[P.parL[n]], P.sizeL[n]);
    if (tid == 0) P.tinL[0] = 0;
    __syncthreads();

    // top-down Euler (pre-order) positions
    for (int d = 1; d <= dmax; ++d) {
        int c = P.hist[d], o = P.off[d];
        for (int i = tid; i < c; i += 256) {
            int n = P.bucket[o + i];
            P.tinL[n] = (unsigned short)((int)P.tinL[P.parL[n]] + 1 + (int)P.sibp[n]);
        }
        __syncthreads();
    }

    for (int n = tid; n < NPB; n += 256) {
        int t = P.tinL[n];
        P.tmpTok[t] = P.tokL[n];
        P.tmpEnd[t] = (unsigned short)(t + P.sizeL[n] - 1);
    }
    __syncthreads();
    for (int t = tid; t < NPB; t += 256) {
        tokD[base + t] = P.tmpTok[t];
        endD[base + t] = P.tmpEnd[t];
    }
}

// ---------------- fused gather + prefix-scan + subtree-max ----------------
// One block = 64 channels (sp*64..sp*64+63), 1024 thr. Full 128 B line per
// node fetched exactly once machine-wide. __launch_bounds__(1024, 8): force
// the allocator to <=64 VGPR so TWO 16-wave blocks fit per CU (VGPR cliff at
// 64 per m69); LDS 73 KB also allows 2. Without this, x[32] pushes past 64
// VGPR -> 1 block/CU -> 4 serial latency-bound rounds instead of 2.
__global__ __launch_bounds__(1024, 8) void scan_k(const int* __restrict__ tokD,
                                                  const unsigned short* __restrict__ endD,
                                                  const unsigned short* __restrict__ Eb,
                                                  float* __restrict__ out) {
    const int b = blockIdx.x & 511, sp = blockIdx.x >> 9, tid = threadIdx.x;
    const long long base = (long long)b * NPB;
    __shared__ unsigned short Sbf[NPB * 64];   // 64000 B: values, then prefix (bf16)
    __shared__ unsigned short endL[NPB];       // 1000 B
    __shared__ float partials[16 * 64];        // 4096 B
    __shared__ float wmax[16 * 64];            // 4096 B

    // DMA gather: node n = (tid>>3)+u*128, chunk q = tid&7 (8 lanes = 128 B/row).
    #pragma unroll
    for (int u = 0; u < 4; ++u) {
        int n = (tid >> 3) + u * 128;
        if (n < NPB) {
            int tok = tokD[base + n];          // 8 consecutive lanes share one int
            const unsigned short* g = &Eb[(long long)tok * DIM + sp * 64 + (tid & 7) * 8];
            __builtin_amdgcn_global_load_lds(
                (const __attribute__((address_space(1))) void*)g,
                (__attribute__((address_space(3))) void*)&Sbf[n * 64 + (tid & 7) * 8],
                16, 0, 0);
        }
    }
    // overlap with DMA flight
    if (tid < NPB) endL[tid] = endD[base + tid];
    __syncthreads();

    const int j = tid & 63, c = tid >> 6;      // wave == chunk c, lane == channel j
    float x[32];
    {   // consume own chunk: bf16 -> f32 running sum in registers
        float run = 0.f;
        #pragma unroll
        for (int k = 0; k < 32; ++k) {
            int t = c * 32 + k;
            float v = (t < NPB)
                ? __uint_as_float((unsigned)Sbf[t * 64 + j] << 16) : 0.f;
            run += v; x[k] = run;
        }
        partials[c * 64 + j] = run;
    }
    __syncthreads();
    float off = 0.f;
    for (int cc = 0; cc < c; ++cc) off += partials[cc * 64 + j];
    #pragma unroll
    for (int k = 0; k < 32; ++k) {   // write back bf16 prefix to OWN slots
        int t = c * 32 + k;
        x[k] += off;
        if (t < NPB) Sbf[t * 64 + j] = f2bf(x[k]);
    }
    __syncthreads();

    // extract: lo from registers (full f32), hi from bf16 prefix
    float m = -INFINITY;
    #pragma unroll
    for (int k = 0; k < 32; ++k) {
        int t = c * 32 + k;
        if (t < NPB) {
            float hi = __uint_as_float((unsigned)Sbf[(int)endL[t] * 64 + j] << 16);
            float lo = (k > 0) ? x[k - 1] : off;
            m = fmaxf(m, hi - lo);
        }
    }
    wmax[c * 64 + j] = m;                      // wave-uniform c: no shfl needed
    __syncthreads();
    if (tid < 64) {
        float mm = wmax[tid];
        #pragma unroll
        for (int w = 1; w < 16; ++w) mm = fmaxf(mm, wmax[w * 64 + tid]);
        out[b * DIM + sp * 64 + tid] = fmaxf(mm, 0.0f);
    }
}

extern "C" void kernel_launch(void* const* d_in, const int* in_sizes, int n_in,
                              void* d_out, int out_size, void* d_ws, size_t ws_size,
                              hipStream_t stream) {
    const int*   tokens = (const int*)d_in[0];
    const int*   parent = (const int*)d_in[1];
    const int*   depth  = (const int*)d_in[2];
    // d_in[3] = node2batch (unused: node2batch[n] == n / 500 by construction)
    const float* emb    = (const float*)d_in[4];
    const float* Wc     = (const float*)d_in[5];
    const float* bc     = (const float*)d_in[6];
    float*       out    = (float*)d_out;

    unsigned short* Eb   = (unsigned short*)d_ws;                   // 12.8 MB bf16
    int*            tokD = (int*)(Eb + (long long)VOCAB * DIM);     // 1 MB
    unsigned short* endD = (unsigned short*)(tokD + B_BATCH * NPB); // 0.5 MB

    prep_gemm<<<NPREP + NGEMM, 256, 0, stream>>>(tokens, parent, depth,
                                                 emb, Wc, bc, tokD, endD, Eb);
    scan_k<<<B_BATCH * 2, 1024, 0, stream>>>(tokD, endD, Eb, out);
}

// Round 4
// 126.503 us; speedup vs baseline: 1.0835x; 1.0835x over previous
//
#include <hip/hip_runtime.h>
#include <hip/hip_bf16.h>

#define B_BATCH 512
#define NPB     500
#define DIM     128
#define VOCAB   50000
#define MAXD    40
#define NPREP   512
#define NGEMM   ((VOCAB + 63) / 64)   // 782

typedef short bf16x8 __attribute__((ext_vector_type(8)));
typedef float f32x4  __attribute__((ext_vector_type(4)));

__device__ __forceinline__ unsigned short f2bf(float x) {
    unsigned u = __float_as_uint(x);
    return (unsigned short)((u + 0x7fffu + ((u >> 16) & 1u)) >> 16);   // RTNE
}

// Prep-branch LDS overlaid with the GEMM branch's 32 KB WcT4 buffer so the
// kernel's static LDS is max(32K, 14.5K) = 32 KB, not the sum.
struct PrepShm {
    int   tokL[NPB];
    int   sizeL[NPB];
    int   childCur[NPB];
    int   tmpTok[NPB];
    int   hist[MAXD + 1], off[MAXD + 1], cur[MAXD + 1];
    int   sdmax;
    unsigned short parL[NPB];
    unsigned short depL[NPB];
    unsigned short sibp[NPB];
    unsigned short tinL[NPB];
    unsigned short bucket[NPB];
    unsigned short tmpEnd[NPB];
};

// ---------- fused prep (blocks 0..511) + MFMA gemm (blocks 512..1293) ----------
__global__ __launch_bounds__(256) void prep_gemm(const int* __restrict__ tokens,
                                                 const int* __restrict__ parent,
                                                 const int* __restrict__ depth,
                                                 const float* __restrict__ emb,
                                                 const float* __restrict__ Wc,
                                                 const float* __restrict__ bc,
                                                 int* __restrict__ tokD,
                                                 unsigned short* __restrict__ endD,
                                                 unsigned short* __restrict__ Eb) {
    __shared__ __align__(16) unsigned char shm[32768];
    const int tid = threadIdx.x;

    if (blockIdx.x >= NPREP) {
        // ================= GEMM branch =================
        // All 4 kc-stages of Wc staged into WcT4[4][128][32] with ONE barrier
        // (stages write disjoint LDS; nothing reads before the sync). emb
        // loads hoisted ahead of staging so HBM latency hides under the
        // Wc convert/write VALU work.
        unsigned short* WcT4 = (unsigned short*)shm;     // 32 KB

        const int lane = tid & 63, w = tid >> 6;
        const int q = lane >> 4, mc = lane & 15;
        const int rowBase = (blockIdx.x - NPREP) * 64;
        const int arow = min(rowBase + w * 16 + mc, VOCAB - 1);   // clamp, no OOB

        // ---- A: issue all 8 emb loads up-front ----
        const float* esrc = &emb[(long long)arow * DIM];
        float4 ev[8];
        #pragma unroll
        for (int kc = 0; kc < 4; ++kc) {
            const float* src = esrc + kc * 32 + q * 8;
            ev[2 * kc]     = *(const float4*)src;
            ev[2 * kc + 1] = *(const float4*)(src + 4);
        }

        // ---- stage all of Wc (bf16, transposed) ----
        const int kk = tid >> 3;           // 0..31 : k within stage
        const int c0 = (tid & 7) * 16;     // col base, 16 cols per thread
        #pragma unroll
        for (int s = 0; s < 4; ++s) {
            const float* wsrc = &Wc[(s * 32 + kk) * DIM + c0];
            float wv[16];
            *(float4*)(wv + 0)  = *(const float4*)(wsrc + 0);
            *(float4*)(wv + 4)  = *(const float4*)(wsrc + 4);
            *(float4*)(wv + 8)  = *(const float4*)(wsrc + 8);
            *(float4*)(wv + 12) = *(const float4*)(wsrc + 12);
            #pragma unroll
            for (int i = 0; i < 16; ++i)
                WcT4[s * 4096 + (c0 + i) * 32 + kk] = f2bf(wv[i]);
        }

        // ---- convert A fragments while staging stores drain ----
        bf16x8 a4[4];
        #pragma unroll
        for (int kc = 0; kc < 4; ++kc) {
            float4 v0 = ev[2 * kc], v1 = ev[2 * kc + 1];
            unsigned short aw[8] = {f2bf(v0.x), f2bf(v0.y), f2bf(v0.z), f2bf(v0.w),
                                    f2bf(v1.x), f2bf(v1.y), f2bf(v1.z), f2bf(v1.w)};
            a4[kc] = *(bf16x8*)aw;
        }
        __syncthreads();   // the ONLY barrier in the GEMM branch

        f32x4 acc[8];
        #pragma unroll
        for (int nt = 0; nt < 8; ++nt) acc[nt] = (f32x4){0.f, 0.f, 0.f, 0.f};

        #pragma unroll
        for (int kc = 0; kc < 4; ++kc) {
            #pragma unroll
            for (int nt = 0; nt < 8; ++nt) {
                bf16x8 bfr = *(bf16x8*)&WcT4[kc * 4096 + (nt * 16 + mc) * 32 + q * 8];
                acc[nt] = __builtin_amdgcn_mfma_f32_16x16x32_bf16(a4[kc], bfr, acc[nt], 0, 0, 0);
            }
        }

        #pragma unroll
        for (int nt = 0; nt < 8; ++nt) {
            float bcv = bc[nt * 16 + mc];
            #pragma unroll
            for (int r = 0; r < 4; ++r) {
                int grow = rowBase + w * 16 + q * 4 + r;
                if (grow < VOCAB)
                    Eb[(long long)grow * DIM + nt * 16 + mc] = f2bf(acc[nt][r] + bcv);
            }
        }
        return;
    }

    // ================= PREP branch =================
    PrepShm& P = *(PrepShm*)shm;

    const int b = blockIdx.x;
    const long long base = (long long)b * NPB;

    if (tid <= MAXD) P.hist[tid] = 0;
    __syncthreads();
    for (int n = tid; n < NPB; n += 256) {
        int d = depth[base + n];
        P.depL[n]  = (unsigned short)d;
        P.parL[n]  = (unsigned short)(n == 0 ? 0 : (int)(parent[base + n] - base));
        P.tokL[n]  = tokens[base + n];
        P.sizeL[n] = 1;
        P.childCur[n] = 0;
        if (n > 0) atomicAdd(&P.hist[d], 1);
    }
    __syncthreads();

    if (tid < 64) {
        int h = (tid >= 1 && tid <= MAXD) ? P.hist[tid] : 0;
        int x = h;
        #pragma unroll
        for (int o = 1; o < 64; o <<= 1) { int y = __shfl_up(x, o, 64); if (tid >= o) x += y; }
        if (tid >= 1 && tid <= MAXD) { P.off[tid] = x - h; P.cur[tid] = x - h; }
        int dm = (h > 0) ? tid : 0;
        #pragma unroll
        for (int o = 32; o; o >>= 1) dm = max(dm, __shfl_down(dm, o));
        if (tid == 0) P.sdmax = dm;
    }
    __syncthreads();

    for (int n = 1 + tid; n < NPB; n += 256)
        P.bucket[atomicAdd(&P.cur[P.depL[n]], 1)] = (unsigned short)n;
    __syncthreads();
    const int dmax = P.sdmax;

    // bottom-up subtree sizes (depth-ordered, atomics within a level)
    for (int d = dmax; d >= 1; --d) {
        int c = P.hist[d], o = P.off[d];
        for (int i = tid; i < c; i += 256) {
            int n = P.bucket[o + i];
            atomicAdd(&P.sizeL[P.parL[n]], P.sizeL[n]);
        }
        __syncthreads();
    }

    // sibling offsets: exclusive prefix of sizes in atomic arrival order
    for (int n = 1 + tid; n < NPB; n += 256)
        P.sibp[n] = (unsigned short)atomicAdd(&P.childCur[P.parL[n]], P.sizeL[n]);
    if (tid == 0) P.tinL[0] = 0;
    __syncthreads();

    // top-down Euler (pre-order) positions
    for (int d = 1; d <= dmax; ++d) {
        int c = P.hist[d], o = P.off[d];
        for (int i = tid; i < c; i += 256) {
            int n = P.bucket[o + i];
            P.tinL[n] = (unsigned short)((int)P.tinL[P.parL[n]] + 1 + (int)P.sibp[n]);
        }
        __syncthreads();
    }

    for (int n = tid; n < NPB; n += 256) {
        int t = P.tinL[n];
        P.tmpTok[t] = P.tokL[n];
        P.tmpEnd[t] = (unsigned short)(t + P.sizeL[n] - 1);
    }
    __syncthreads();
    for (int t = tid; t < NPB; t += 256) {
        tokD[base + t] = P.tmpTok[t];
        endD[base + t] = P.tmpEnd[t];
    }
}

// ---------------- fused gather + prefix-scan + subtree-max ----------------
// Round-2 winner restored VERBATIM. __launch_bounds__(1024) with NO min-wave
// spec: Round 3 proved forcing 8 waves/EU (<=64 VGPR) makes x[32] spill to
// scratch, costing +12.5 us — far more than the occupancy doubling gains.
// One block = 64 channels (sp*64..sp*64+63), 1024 thr. Full 128 B line per
// node fetched exactly once machine-wide.
__global__ __launch_bounds__(1024) void scan_k(const int* __restrict__ tokD,
                                               const unsigned short* __restrict__ endD,
                                               const unsigned short* __restrict__ Eb,
                                               float* __restrict__ out) {
    const int b = blockIdx.x & 511, sp = blockIdx.x >> 9, tid = threadIdx.x;
    const long long base = (long long)b * NPB;
    __shared__ unsigned short Sbf[NPB * 64];   // 64000 B: values, then prefix (bf16)
    __shared__ unsigned short endL[NPB];       // 1000 B
    __shared__ float partials[16 * 64];        // 4096 B
    __shared__ float wmax[16 * 64];            // 4096 B

    // DMA gather: node n = (tid>>3)+u*128, chunk q = tid&7 (8 lanes = 128 B/row).
    #pragma unroll
    for (int u = 0; u < 4; ++u) {
        int n = (tid >> 3) + u * 128;
        if (n < NPB) {
            int tok = tokD[base + n];          // 8 consecutive lanes share one int
            const unsigned short* g = &Eb[(long long)tok * DIM + sp * 64 + (tid & 7) * 8];
            __builtin_amdgcn_global_load_lds(
                (const __attribute__((address_space(1))) void*)g,
                (__attribute__((address_space(3))) void*)&Sbf[n * 64 + (tid & 7) * 8],
                16, 0, 0);
        }
    }
    // overlap with DMA flight
    if (tid < NPB) endL[tid] = endD[base + tid];
    __syncthreads();

    const int j = tid & 63, c = tid >> 6;      // wave == chunk c, lane == channel j
    float x[32];
    {   // consume own chunk: bf16 -> f32 running sum in registers
        float run = 0.f;
        #pragma unroll
        for (int k = 0; k < 32; ++k) {
            int t = c * 32 + k;
            float v = (t < NPB)
                ? __uint_as_float((unsigned)Sbf[t * 64 + j] << 16) : 0.f;
            run += v; x[k] = run;
        }
        partials[c * 64 + j] = run;
    }
    __syncthreads();
    float off = 0.f;
    for (int cc = 0; cc < c; ++cc) off += partials[cc * 64 + j];
    #pragma unroll
    for (int k = 0; k < 32; ++k) {   // write back bf16 prefix to OWN slots
        int t = c * 32 + k;
        x[k] += off;
        if (t < NPB) Sbf[t * 64 + j] = f2bf(x[k]);
    }
    __syncthreads();

    // extract: lo from registers (full f32), hi from bf16 prefix
    float m = -INFINITY;
    #pragma unroll
    for (int k = 0; k < 32; ++k) {
        int t = c * 32 + k;
        if (t < NPB) {
            float hi = __uint_as_float((unsigned)Sbf[(int)endL[t] * 64 + j] << 16);
            float lo = (k > 0) ? x[k - 1] : off;
            m = fmaxf(m, hi - lo);
        }
    }
    wmax[c * 64 + j] = m;                      // wave-uniform c: no shfl needed
    __syncthreads();
    if (tid < 64) {
        float mm = wmax[tid];
        #pragma unroll
        for (int w = 1; w < 16; ++w) mm = fmaxf(mm, wmax[w * 64 + tid]);
        out[b * DIM + sp * 64 + tid] = fmaxf(mm, 0.0f);
    }
}

extern "C" void kernel_launch(void* const* d_in, const int* in_sizes, int n_in,
                              void* d_out, int out_size, void* d_ws, size_t ws_size,
                              hipStream_t stream) {
    const int*   tokens = (const int*)d_in[0];
    const int*   parent = (const int*)d_in[1];
    const int*   depth  = (const int*)d_in[2];
    // d_in[3] = node2batch (unused: node2batch[n] == n / 500 by construction)
    const float* emb    = (const float*)d_in[4];
    const float* Wc     = (const float*)d_in[5];
    const float* bc     = (const float*)d_in[6];
    float*       out    = (float*)d_out;

    unsigned short* Eb   = (unsigned short*)d_ws;                   // 12.8 MB bf16
    int*            tokD = (int*)(Eb + (long long)VOCAB * DIM);     // 1 MB
    unsigned short* endD = (unsigned short*)(tokD + B_BATCH * NPB); // 0.5 MB

    prep_gemm<<<NPREP + NGEMM, 256, 0, stream>>>(tokens, parent, depth,
                                                 emb, Wc, bc, tokD, endD, Eb);
    scan_k<<<B_BATCH * 2, 1024, 0, stream>>>(tokD, endD, Eb, out);
}

// Round 5
// 126.007 us; speedup vs baseline: 1.0878x; 1.0039x over previous
//
#include <hip/hip_runtime.h>
#include <hip/hip_bf16.h>

#define B_BATCH 512
#define NPB     500
#define DIM     128
#define VOCAB   50000
#define MAXD    40
#define NPREP   512
#define NGEMM   ((VOCAB + 63) / 64)   // 782

typedef short bf16x8 __attribute__((ext_vector_type(8)));
typedef float f32x4  __attribute__((ext_vector_type(4)));

__device__ __forceinline__ unsigned short f2bf(float x) {
    unsigned u = __float_as_uint(x);
    return (unsigned short)((u + 0x7fffu + ((u >> 16) & 1u)) >> 16);   // RTNE
}

// Prep-branch LDS overlaid with the GEMM branch's 8 KB WcT buffer:
// static LDS = max(8 KB, 11 KB) = 11 KB (was 22.5 KB in R2, 32 KB in R4).
struct PrepShm {
    int   tokL[NPB];
    int   sizeL[NPB];
    int   childCur[NPB];
    int   tmpTok[NPB];
    unsigned short parL[NPB];
    unsigned short sibp[NPB];
    unsigned short tmpEnd[NPB];
};   // 11000 B

// ---------- fused prep (blocks 0..511) + MFMA gemm (blocks 512..1293) ----------
__global__ __launch_bounds__(256) void prep_gemm(const int* __restrict__ tokens,
                                                 const int* __restrict__ parent,
                                                 const int* __restrict__ depth,
                                                 const float* __restrict__ emb,
                                                 const float* __restrict__ Wc,
                                                 const float* __restrict__ bc,
                                                 int* __restrict__ tokD,
                                                 unsigned short* __restrict__ endD,
                                                 unsigned short* __restrict__ Eb) {
    __shared__ __align__(16) unsigned char shm[11264];
    const int tid = threadIdx.x;

    if (blockIdx.x >= NPREP) {
        // ================= GEMM branch (Round-2 proven version) =================
        unsigned short* WcT = (unsigned short*)shm;      // 8 KB per stage

        const int lane = tid & 63, w = tid >> 6;
        const int q = lane >> 4, mc = lane & 15;
        const int rowBase = (blockIdx.x - NPREP) * 64;
        const int arow = min(rowBase + w * 16 + mc, VOCAB - 1);   // clamp, no OOB

        f32x4 acc[8];
        #pragma unroll
        for (int nt = 0; nt < 8; ++nt) acc[nt] = (f32x4){0.f, 0.f, 0.f, 0.f};

        const int kk = tid >> 3;           // 0..31 : k within stage
        const int c0 = (tid & 7) * 16;     // col base, 16 cols per thread

        #pragma unroll
        for (int kc = 0; kc < 4; ++kc) {
            // ---- stage Wc[kc*32 .. kc*32+31][*] transposed to bf16 ----
            const float* wsrc = &Wc[(kc * 32 + kk) * DIM + c0];
            float wv[16];
            *(float4*)(wv + 0)  = *(const float4*)(wsrc + 0);
            *(float4*)(wv + 4)  = *(const float4*)(wsrc + 4);
            *(float4*)(wv + 8)  = *(const float4*)(wsrc + 8);
            *(float4*)(wv + 12) = *(const float4*)(wsrc + 12);
            __syncthreads();   // previous stage's readers done (loads in flight)
            #pragma unroll
            for (int i = 0; i < 16; ++i)
                WcT[(c0 + i) * 32 + kk] = f2bf(wv[i]);
            __syncthreads();

            // ---- A fragment from emb ----
            const float* src = &emb[(long long)arow * DIM + kc * 32 + q * 8];
            float4 v0 = *(const float4*)src;
            float4 v1 = *(const float4*)(src + 4);
            unsigned short aw[8] = {f2bf(v0.x), f2bf(v0.y), f2bf(v0.z), f2bf(v0.w),
                                    f2bf(v1.x), f2bf(v1.y), f2bf(v1.z), f2bf(v1.w)};
            bf16x8 a = *(bf16x8*)aw;

            #pragma unroll
            for (int nt = 0; nt < 8; ++nt) {
                bf16x8 bfr = *(bf16x8*)&WcT[(nt * 16 + mc) * 32 + q * 8];
                acc[nt] = __builtin_amdgcn_mfma_f32_16x16x32_bf16(a, bfr, acc[nt], 0, 0, 0);
            }
        }

        #pragma unroll
        for (int nt = 0; nt < 8; ++nt) {
            float bcv = bc[nt * 16 + mc];
            #pragma unroll
            for (int r = 0; r < 4; ++r) {
                int grow = rowBase + w * 16 + q * 4 + r;
                if (grow < VOCAB)
                    Eb[(long long)grow * DIM + nt * 16 + mc] = f2bf(acc[nt][r] + bcv);
            }
        }
        return;
    }

    // ================= PREP branch: barrier-free chain walks =================
    // Old version: two depth-level loops with ~80 __syncthreads on the
    // critical path. New: (1) size via per-node ancestor walk with LDS
    // atomicAdd (contributions independent -> no ordering; root excluded,
    // its size is NPB by definition); (2) sibp unchanged (one atomic pass);
    // (3) tin telescopes to depth[n] + sum of sibp along the parent chain.
    // 5 barriers total. Avg chain length ~ln(500)=6, max <40.
    PrepShm& P = *(PrepShm*)shm;

    const int b = blockIdx.x;
    const long long base = (long long)b * NPB;

    const int n0 = tid, n1 = tid + 256;
    int d0 = 0, d1 = 0;
    {
        d0 = (int)depth[base + n0];
        P.parL[n0]     = (unsigned short)(n0 == 0 ? 0 : (int)(parent[base + n0] - base));
        P.tokL[n0]     = tokens[base + n0];
        P.sizeL[n0]    = 1;
        P.childCur[n0] = 0;
        if (n1 < NPB) {
            d1 = (int)depth[base + n1];
            P.parL[n1]     = (unsigned short)(int)(parent[base + n1] - base);
            P.tokL[n1]     = tokens[base + n1];
            P.sizeL[n1]    = 1;
            P.childCur[n1] = 0;
        }
    }
    __syncthreads();

    // size: each node +1 to every proper ancestor except root
    if (n0 >= 1) {
        int p = P.parL[n0];
        while (p != 0) { atomicAdd(&P.sizeL[p], 1); p = P.parL[p]; }
    }
    if (n1 < NPB) {
        int p = P.parL[n1];
        while (p != 0) { atomicAdd(&P.sizeL[p], 1); p = P.parL[p]; }
    }
    __syncthreads();

    // sibling offsets: exclusive prefix of sizes in atomic arrival order
    if (n0 >= 1) P.sibp[n0] = (unsigned short)atomicAdd(&P.childCur[P.parL[n0]], P.sizeL[n0]);
    if (n1 < NPB) P.sibp[n1] = (unsigned short)atomicAdd(&P.childCur[P.parL[n1]], P.sizeL[n1]);
    __syncthreads();

    // tin = depth[n] + sum of sibp along chain (excl. root); scatter outputs
    {
        int t = d0, a = n0;
        while (a != 0) { t += P.sibp[a]; a = P.parL[a]; }
        P.tmpTok[t] = P.tokL[n0];
        P.tmpEnd[t] = (unsigned short)(n0 == 0 ? NPB - 1 : t + P.sizeL[n0] - 1);
    }
    if (n1 < NPB) {
        int t = d1, a = n1;
        while (a != 0) { t += P.sibp[a]; a = P.parL[a]; }
        P.tmpTok[t] = P.tokL[n1];
        P.tmpEnd[t] = (unsigned short)(t + P.sizeL[n1] - 1);
    }
    __syncthreads();

    for (int t = tid; t < NPB; t += 256) {
        tokD[base + t] = P.tmpTok[t];
        endD[base + t] = P.tmpEnd[t];
    }
}

// ---------------- fused gather + prefix-scan + subtree-max ----------------
// Round-2 winner VERBATIM. __launch_bounds__(1024) with NO min-wave spec
// (R3 proved forcing <=64 VGPR spills x[32] to scratch: +12.5 us).
__global__ __launch_bounds__(1024) void scan_k(const int* __restrict__ tokD,
                                               const unsigned short* __restrict__ endD,
                                               const unsigned short* __restrict__ Eb,
                                               float* __restrict__ out) {
    const int b = blockIdx.x & 511, sp = blockIdx.x >> 9, tid = threadIdx.x;
    const long long base = (long long)b * NPB;
    __shared__ unsigned short Sbf[NPB * 64];   // 64000 B: values, then prefix (bf16)
    __shared__ unsigned short endL[NPB];       // 1000 B
    __shared__ float partials[16 * 64];        // 4096 B
    __shared__ float wmax[16 * 64];            // 4096 B

    // DMA gather: node n = (tid>>3)+u*128, chunk q = tid&7 (8 lanes = 128 B/row).
    #pragma unroll
    for (int u = 0; u < 4; ++u) {
        int n = (tid >> 3) + u * 128;
        if (n < NPB) {
            int tok = tokD[base + n];          // 8 consecutive lanes share one int
            const unsigned short* g = &Eb[(long long)tok * DIM + sp * 64 + (tid & 7) * 8];
            __builtin_amdgcn_global_load_lds(
                (const __attribute__((address_space(1))) void*)g,
                (__attribute__((address_space(3))) void*)&Sbf[n * 64 + (tid & 7) * 8],
                16, 0, 0);
        }
    }
    // overlap with DMA flight
    if (tid < NPB) endL[tid] = endD[base + tid];
    __syncthreads();

    const int j = tid & 63, c = tid >> 6;      // wave == chunk c, lane == channel j
    float x[32];
    {   // consume own chunk: bf16 -> f32 running sum in registers
        float run = 0.f;
        #pragma unroll
        for (int k = 0; k < 32; ++k) {
            int t = c * 32 + k;
            float v = (t < NPB)
                ? __uint_as_float((unsigned)Sbf[t * 64 + j] << 16) : 0.f;
            run += v; x[k] = run;
        }
        partials[c * 64 + j] = run;
    }
    __syncthreads();
    float off = 0.f;
    for (int cc = 0; cc < c; ++cc) off += partials[cc * 64 + j];
    #pragma unroll
    for (int k = 0; k < 32; ++k) {   // write back bf16 prefix to OWN slots
        int t = c * 32 + k;
        x[k] += off;
        if (t < NPB) Sbf[t * 64 + j] = f2bf(x[k]);
    }
    __syncthreads();

    // extract: lo from registers (full f32), hi from bf16 prefix
    float m = -INFINITY;
    #pragma unroll
    for (int k = 0; k < 32; ++k) {
        int t = c * 32 + k;
        if (t < NPB) {
            float hi = __uint_as_float((unsigned)Sbf[(int)endL[t] * 64 + j] << 16);
            float lo = (k > 0) ? x[k - 1] : off;
            m = fmaxf(m, hi - lo);
        }
    }
    wmax[c * 64 + j] = m;                      // wave-uniform c: no shfl needed
    __syncthreads();
    if (tid < 64) {
        float mm = wmax[tid];
        #pragma unroll
        for (int w = 1; w < 16; ++w) mm = fmaxf(mm, wmax[w * 64 + tid]);
        out[b * DIM + sp * 64 + tid] = fmaxf(mm, 0.0f);
    }
}

extern "C" void kernel_launch(void* const* d_in, const int* in_sizes, int n_in,
                              void* d_out, int out_size, void* d_ws, size_t ws_size,
                              hipStream_t stream) {
    const int*   tokens = (const int*)d_in[0];
    const int*   parent = (const int*)d_in[1];
    const int*   depth  = (const int*)d_in[2];
    // d_in[3] = node2batch (unused: node2batch[n] == n / 500 by construction)
    const float* emb    = (const float*)d_in[4];
    const float* Wc     = (const float*)d_in[5];
    const float* bc     = (const float*)d_in[6];
    float*       out    = (float*)d_out;

    unsigned short* Eb   = (unsigned short*)d_ws;                   // 12.8 MB bf16
    int*            tokD = (int*)(Eb + (long long)VOCAB * DIM);     // 1 MB
    unsigned short* endD = (unsigned short*)(tokD + B_BATCH * NPB); // 0.5 MB

    prep_gemm<<<NPREP + NGEMM, 256, 0, stream>>>(tokens, parent, depth,
                                                 emb, Wc, bc, tokD, endD, Eb);
    scan_k<<<B_BATCH * 2, 1024, 0, stream>>>(tokD, endD, Eb, out);
}

// Round 6
// 123.094 us; speedup vs baseline: 1.1135x; 1.0237x over previous
//
#include <hip/hip_runtime.h>
#include <hip/hip_bf16.h>

#define B_BATCH 512
#define NPB     500
#define DIM     128
#define VOCAB   50000
#define MAXD    40
#define NPREP   512
#define NGEMM   ((VOCAB + 63) / 64)   // 782

typedef short bf16x8 __attribute__((ext_vector_type(8)));
typedef float f32x4  __attribute__((ext_vector_type(4)));

__device__ __forceinline__ unsigned short f2bf(float x) {
    unsigned u = __float_as_uint(x);
    return (unsigned short)((u + 0x7fffu + ((u >> 16) & 1u)) >> 16);   // RTNE
}

// Prep-branch LDS overlaid with the GEMM branch's 8 KB WcT buffer:
// static LDS = max(8 KB, 11 KB) = 11 KB.
struct PrepShm {
    int   tokL[NPB];
    int   sizeL[NPB];
    int   childCur[NPB];
    int   tmpTok[NPB];
    unsigned short parL[NPB];
    unsigned short sibp[NPB];
    unsigned short tmpEnd[NPB];
};   // 11000 B

// ---------- fused prep (blocks 0..511) + MFMA gemm (blocks 512..1293) ----------
__global__ __launch_bounds__(256) void prep_gemm(const int* __restrict__ tokens,
                                                 const int* __restrict__ parent,
                                                 const int* __restrict__ depth,
                                                 const float* __restrict__ emb,
                                                 const float* __restrict__ Wc,
                                                 const float* __restrict__ bc,
                                                 int* __restrict__ tokD,
                                                 unsigned short* __restrict__ endD,
                                                 unsigned short* __restrict__ Eb) {
    __shared__ __align__(16) unsigned char shm[11264];
    const int tid = threadIdx.x;

    if (blockIdx.x >= NPREP) {
        // ================= GEMM branch (Round-2 proven version) =================
        unsigned short* WcT = (unsigned short*)shm;      // 8 KB per stage

        const int lane = tid & 63, w = tid >> 6;
        const int q = lane >> 4, mc = lane & 15;
        const int rowBase = (blockIdx.x - NPREP) * 64;
        const int arow = min(rowBase + w * 16 + mc, VOCAB - 1);   // clamp, no OOB

        f32x4 acc[8];
        #pragma unroll
        for (int nt = 0; nt < 8; ++nt) acc[nt] = (f32x4){0.f, 0.f, 0.f, 0.f};

        const int kk = tid >> 3;           // 0..31 : k within stage
        const int c0 = (tid & 7) * 16;     // col base, 16 cols per thread

        #pragma unroll
        for (int kc = 0; kc < 4; ++kc) {
            // ---- stage Wc[kc*32 .. kc*32+31][*] transposed to bf16 ----
            const float* wsrc = &Wc[(kc * 32 + kk) * DIM + c0];
            float wv[16];
            *(float4*)(wv + 0)  = *(const float4*)(wsrc + 0);
            *(float4*)(wv + 4)  = *(const float4*)(wsrc + 4);
            *(float4*)(wv + 8)  = *(const float4*)(wsrc + 8);
            *(float4*)(wv + 12) = *(const float4*)(wsrc + 12);
            __syncthreads();   // previous stage's readers done (loads in flight)
            #pragma unroll
            for (int i = 0; i < 16; ++i)
                WcT[(c0 + i) * 32 + kk] = f2bf(wv[i]);
            __syncthreads();

            // ---- A fragment from emb ----
            const float* src = &emb[(long long)arow * DIM + kc * 32 + q * 8];
            float4 v0 = *(const float4*)src;
            float4 v1 = *(const float4*)(src + 4);
            unsigned short aw[8] = {f2bf(v0.x), f2bf(v0.y), f2bf(v0.z), f2bf(v0.w),
                                    f2bf(v1.x), f2bf(v1.y), f2bf(v1.z), f2bf(v1.w)};
            bf16x8 a = *(bf16x8*)aw;

            #pragma unroll
            for (int nt = 0; nt < 8; ++nt) {
                bf16x8 bfr = *(bf16x8*)&WcT[(nt * 16 + mc) * 32 + q * 8];
                acc[nt] = __builtin_amdgcn_mfma_f32_16x16x32_bf16(a, bfr, acc[nt], 0, 0, 0);
            }
        }

        #pragma unroll
        for (int nt = 0; nt < 8; ++nt) {
            float bcv = bc[nt * 16 + mc];
            #pragma unroll
            for (int r = 0; r < 4; ++r) {
                int grow = rowBase + w * 16 + q * 4 + r;
                if (grow < VOCAB)
                    Eb[(long long)grow * DIM + nt * 16 + mc] = f2bf(acc[nt][r] + bcv);
            }
        }
        return;
    }

    // ================= PREP branch: barrier-free chain walks (R5) =================
    PrepShm& P = *(PrepShm*)shm;

    const int b = blockIdx.x;
    const long long base = (long long)b * NPB;

    const int n0 = tid, n1 = tid + 256;
    int d0 = 0, d1 = 0;
    {
        d0 = (int)depth[base + n0];
        P.parL[n0]     = (unsigned short)(n0 == 0 ? 0 : (int)(parent[base + n0] - base));
        P.tokL[n0]     = tokens[base + n0];
        P.sizeL[n0]    = 1;
        P.childCur[n0] = 0;
        if (n1 < NPB) {
            d1 = (int)depth[base + n1];
            P.parL[n1]     = (unsigned short)(int)(parent[base + n1] - base);
            P.tokL[n1]     = tokens[base + n1];
            P.sizeL[n1]    = 1;
            P.childCur[n1] = 0;
        }
    }
    __syncthreads();

    // size: each node +1 to every proper ancestor except root
    if (n0 >= 1) {
        int p = P.parL[n0];
        while (p != 0) { atomicAdd(&P.sizeL[p], 1); p = P.parL[p]; }
    }
    if (n1 < NPB) {
        int p = P.parL[n1];
        while (p != 0) { atomicAdd(&P.sizeL[p], 1); p = P.parL[p]; }
    }
    __syncthreads();

    // sibling offsets: exclusive prefix of sizes in atomic arrival order
    if (n0 >= 1) P.sibp[n0] = (unsigned short)atomicAdd(&P.childCur[P.parL[n0]], P.sizeL[n0]);
    if (n1 < NPB) P.sibp[n1] = (unsigned short)atomicAdd(&P.childCur[P.parL[n1]], P.sizeL[n1]);
    __syncthreads();

    // tin = depth[n] + sum of sibp along chain (excl. root); scatter outputs
    {
        int t = d0, a = n0;
        while (a != 0) { t += P.sibp[a]; a = P.parL[a]; }
        P.tmpTok[t] = P.tokL[n0];
        P.tmpEnd[t] = (unsigned short)(n0 == 0 ? NPB - 1 : t + P.sizeL[n0] - 1);
    }
    if (n1 < NPB) {
        int t = d1, a = n1;
        while (a != 0) { t += P.sibp[a]; a = P.parL[a]; }
        P.tmpTok[t] = P.tokL[n1];
        P.tmpEnd[t] = (unsigned short)(t + P.sizeL[n1] - 1);
    }
    __syncthreads();

    for (int t = tid; t < NPB; t += 256) {
        tokD[base + t] = P.tmpTok[t];
        endD[base + t] = P.tmpEnd[t];
    }
}

// ---------------- fused gather + prefix-scan + subtree-max ----------------
// CHANNEL-PAIRED: each thread owns channels (2jp, 2jp+1) — adjacent ushorts
// in one LDS dword — so every consume/writeback/extract access is ONE b32
// instead of two scalar u16 ops: per-thread LDS instrs ~104 -> ~55. Remap:
// jp = tid&31 (pair), c = tid>>5 (32 chunks x 16 nodes). Bank audit: dword
// idx = t*32+jp -> half-wave spans banks 0..31, halves 2-way alias (free,
// m136); extract's random rows likewise. wmax overlays partials (all
// partials reads complete before the post-writeback barrier). LDS 73 KB.
// No forced min-waves (R3: forcing <=64 VGPR spills x[] -> +12.5 us).
__global__ __launch_bounds__(1024) void scan_k(const int* __restrict__ tokD,
                                               const unsigned short* __restrict__ endD,
                                               const unsigned short* __restrict__ Eb,
                                               float* __restrict__ out) {
    const int b = blockIdx.x & 511, sp = blockIdx.x >> 9, tid = threadIdx.x;
    const long long base = (long long)b * NPB;
    __shared__ unsigned short Sbf[NPB * 64];   // 64000 B: values, then prefix (bf16)
    __shared__ unsigned short endL[NPB];       // 1000 B
    __shared__ float2 pw[32 * 32];             // 8192 B: partials, then wmax

    // DMA gather: node n = (tid>>3)+u*128, chunk q = tid&7 (8 lanes = 128 B/row).
    #pragma unroll
    for (int u = 0; u < 4; ++u) {
        int n = (tid >> 3) + u * 128;
        if (n < NPB) {
            int tok = tokD[base + n];          // 8 consecutive lanes share one int
            const unsigned short* g = &Eb[(long long)tok * DIM + sp * 64 + (tid & 7) * 8];
            __builtin_amdgcn_global_load_lds(
                (const __attribute__((address_space(1))) void*)g,
                (__attribute__((address_space(3))) void*)&Sbf[n * 64 + (tid & 7) * 8],
                16, 0, 0);
        }
    }
    // overlap with DMA flight
    if (tid < NPB) endL[tid] = endD[base + tid];
    __syncthreads();

    const int jp = tid & 31;      // channel pair: channels 2jp, 2jp+1
    const int c  = tid >> 5;      // chunk 0..31, 16 nodes each (31 has tail)
    float x0[16], x1[16];
    {   // consume own chunk: one b32 read = both channels' bf16 values
        float run0 = 0.f, run1 = 0.f;
        #pragma unroll
        for (int k = 0; k < 16; ++k) {
            int t = c * 16 + k;
            unsigned v = (t < NPB) ? *(const unsigned*)&Sbf[t * 64 + jp * 2] : 0u;
            run0 += __uint_as_float(v << 16);
            run1 += __uint_as_float(v & 0xffff0000u);
            x0[k] = run0; x1[k] = run1;
        }
        pw[c * 32 + jp] = (float2){run0, run1};
    }
    __syncthreads();
    float off0 = 0.f, off1 = 0.f;
    for (int cc = 0; cc < c; ++cc) {
        float2 p = pw[cc * 32 + jp];
        off0 += p.x; off1 += p.y;
    }
    #pragma unroll
    for (int k = 0; k < 16; ++k) {   // write back packed bf16 prefix to OWN slots
        int t = c * 16 + k;
        x0[k] += off0; x1[k] += off1;
        if (t < NPB) {
            unsigned pk = ((unsigned)f2bf(x1[k]) << 16) | (unsigned)f2bf(x0[k]);
            *(unsigned*)&Sbf[t * 64 + jp * 2] = pk;
        }
    }
    __syncthreads();   // also: all pw(partials) reads are done -> reuse as wmax

    // extract: lo from registers (full f32), hi from packed bf16 prefix
    float m0 = -INFINITY, m1 = -INFINITY;
    #pragma unroll
    for (int k = 0; k < 16; ++k) {
        int t = c * 16 + k;
        if (t < NPB) {
            unsigned pk = *(const unsigned*)&Sbf[(int)endL[t] * 64 + jp * 2];
            float hi0 = __uint_as_float(pk << 16);
            float hi1 = __uint_as_float(pk & 0xffff0000u);
            float lo0 = (k > 0) ? x0[k - 1] : off0;
            float lo1 = (k > 0) ? x1[k - 1] : off1;
            m0 = fmaxf(m0, hi0 - lo0);
            m1 = fmaxf(m1, hi1 - lo1);
        }
    }
    pw[c * 32 + jp] = (float2){m0, m1};        // wave-uniform c: no shfl needed
    __syncthreads();
    if (tid < 32) {
        float2 mm = pw[tid];
        #pragma unroll
        for (int w = 1; w < 32; ++w) {
            float2 p = pw[w * 32 + tid];
            mm.x = fmaxf(mm.x, p.x);
            mm.y = fmaxf(mm.y, p.y);
        }
        float2 o = (float2){fmaxf(mm.x, 0.0f), fmaxf(mm.y, 0.0f)};
        *(float2*)&out[b * DIM + sp * 64 + 2 * tid] = o;
    }
}

extern "C" void kernel_launch(void* const* d_in, const int* in_sizes, int n_in,
                              void* d_out, int out_size, void* d_ws, size_t ws_size,
                              hipStream_t stream) {
    const int*   tokens = (const int*)d_in[0];
    const int*   parent = (const int*)d_in[1];
    const int*   depth  = (const int*)d_in[2];
    // d_in[3] = node2batch (unused: node2batch[n] == n / 500 by construction)
    const float* emb    = (const float*)d_in[4];
    const float* Wc     = (const float*)d_in[5];
    const float* bc     = (const float*)d_in[6];
    float*       out    = (float*)d_out;

    unsigned short* Eb   = (unsigned short*)d_ws;                   // 12.8 MB bf16
    int*            tokD = (int*)(Eb + (long long)VOCAB * DIM);     // 1 MB
    unsigned short* endD = (unsigned short*)(tokD + B_BATCH * NPB); // 0.5 MB

    prep_gemm<<<NPREP + NGEMM, 256, 0, stream>>>(tokens, parent, depth,
                                                 emb, Wc, bc, tokD, endD, Eb);
    scan_k<<<B_BATCH * 2, 1024, 0, stream>>>(tokD, endD, Eb, out);
}

// Round 7
// 121.235 us; speedup vs baseline: 1.1306x; 1.0153x over previous
//
#include <hip/hip_runtime.h>
#include <hip/hip_bf16.h>

#define B_BATCH 512
#define NPB     500
#define DIM     128
#define VOCAB   50000
#define MAXD    40
#define NPREP   512
#define NGEMM   ((VOCAB + 63) / 64)   // 782

typedef short bf16x8 __attribute__((ext_vector_type(8)));
typedef float f32x4  __attribute__((ext_vector_type(4)));

__device__ __forceinline__ unsigned short f2bf(float x) {
    unsigned u = __float_as_uint(x);
    return (unsigned short)((u + 0x7fffu + ((u >> 16) & 1u)) >> 16);   // RTNE
}

// Prep-branch LDS overlaid with the GEMM branch's 8 KB WcT buffer:
// static LDS = max(8 KB, 11 KB) = 11 KB.
struct PrepShm {
    int   tokL[NPB];
    int   sizeL[NPB];
    int   childCur[NPB];
    int   tmpTok[NPB];
    unsigned short parL[NPB];
    unsigned short sibp[NPB];
    unsigned short tmpEnd[NPB];
};   // 11000 B

// ---------- fused prep (blocks 0..511) + MFMA gemm (blocks 512..1293) ----------
__global__ __launch_bounds__(256) void prep_gemm(const int* __restrict__ tokens,
                                                 const int* __restrict__ parent,
                                                 const int* __restrict__ depth,
                                                 const float* __restrict__ emb,
                                                 const float* __restrict__ Wc,
                                                 const float* __restrict__ bc,
                                                 int* __restrict__ tokD,
                                                 unsigned short* __restrict__ endD,
                                                 unsigned short* __restrict__ Eb) {
    __shared__ __align__(16) unsigned char shm[11264];
    const int tid = threadIdx.x;

    if (blockIdx.x >= NPREP) {
        // ================= GEMM branch (Round-2 proven version) =================
        unsigned short* WcT = (unsigned short*)shm;      // 8 KB per stage

        const int lane = tid & 63, w = tid >> 6;
        const int q = lane >> 4, mc = lane & 15;
        const int rowBase = (blockIdx.x - NPREP) * 64;
        const int arow = min(rowBase + w * 16 + mc, VOCAB - 1);   // clamp, no OOB

        f32x4 acc[8];
        #pragma unroll
        for (int nt = 0; nt < 8; ++nt) acc[nt] = (f32x4){0.f, 0.f, 0.f, 0.f};

        const int kk = tid >> 3;           // 0..31 : k within stage
        const int c0 = (tid & 7) * 16;     // col base, 16 cols per thread

        #pragma unroll
        for (int kc = 0; kc < 4; ++kc) {
            // ---- stage Wc[kc*32 .. kc*32+31][*] transposed to bf16 ----
            const float* wsrc = &Wc[(kc * 32 + kk) * DIM + c0];
            float wv[16];
            *(float4*)(wv + 0)  = *(const float4*)(wsrc + 0);
            *(float4*)(wv + 4)  = *(const float4*)(wsrc + 4);
            *(float4*)(wv + 8)  = *(const float4*)(wsrc + 8);
            *(float4*)(wv + 12) = *(const float4*)(wsrc + 12);
            __syncthreads();   // previous stage's readers done (loads in flight)
            #pragma unroll
            for (int i = 0; i < 16; ++i)
                WcT[(c0 + i) * 32 + kk] = f2bf(wv[i]);
            __syncthreads();

            // ---- A fragment from emb ----
            const float* src = &emb[(long long)arow * DIM + kc * 32 + q * 8];
            float4 v0 = *(const float4*)src;
            float4 v1 = *(const float4*)(src + 4);
            unsigned short aw[8] = {f2bf(v0.x), f2bf(v0.y), f2bf(v0.z), f2bf(v0.w),
                                    f2bf(v1.x), f2bf(v1.y), f2bf(v1.z), f2bf(v1.w)};
            bf16x8 a = *(bf16x8*)aw;

            #pragma unroll
            for (int nt = 0; nt < 8; ++nt) {
                bf16x8 bfr = *(bf16x8*)&WcT[(nt * 16 + mc) * 32 + q * 8];
                acc[nt] = __builtin_amdgcn_mfma_f32_16x16x32_bf16(a, bfr, acc[nt], 0, 0, 0);
            }
        }

        #pragma unroll
        for (int nt = 0; nt < 8; ++nt) {
            float bcv = bc[nt * 16 + mc];
            #pragma unroll
            for (int r = 0; r < 4; ++r) {
                int grow = rowBase + w * 16 + q * 4 + r;
                if (grow < VOCAB)
                    Eb[(long long)grow * DIM + nt * 16 + mc] = f2bf(acc[nt][r] + bcv);
            }
        }
        return;
    }

    // ================= PREP branch: barrier-free chain walks (R5) =================
    PrepShm& P = *(PrepShm*)shm;

    const int b = blockIdx.x;
    const long long base = (long long)b * NPB;

    const int n0 = tid, n1 = tid + 256;
    int d0 = 0, d1 = 0;
    {
        d0 = (int)depth[base + n0];
        P.parL[n0]     = (unsigned short)(n0 == 0 ? 0 : (int)(parent[base + n0] - base));
        P.tokL[n0]     = tokens[base + n0];
        P.sizeL[n0]    = 1;
        P.childCur[n0] = 0;
        if (n1 < NPB) {
            d1 = (int)depth[base + n1];
            P.parL[n1]     = (unsigned short)(int)(parent[base + n1] - base);
            P.tokL[n1]     = tokens[base + n1];
            P.sizeL[n1]    = 1;
            P.childCur[n1] = 0;
        }
    }
    __syncthreads();

    // size: each node +1 to every proper ancestor except root
    if (n0 >= 1) {
        int p = P.parL[n0];
        while (p != 0) { atomicAdd(&P.sizeL[p], 1); p = P.parL[p]; }
    }
    if (n1 < NPB) {
        int p = P.parL[n1];
        while (p != 0) { atomicAdd(&P.sizeL[p], 1); p = P.parL[p]; }
    }
    __syncthreads();

    // sibling offsets: exclusive prefix of sizes in atomic arrival order
    if (n0 >= 1) P.sibp[n0] = (unsigned short)atomicAdd(&P.childCur[P.parL[n0]], P.sizeL[n0]);
    if (n1 < NPB) P.sibp[n1] = (unsigned short)atomicAdd(&P.childCur[P.parL[n1]], P.sizeL[n1]);
    __syncthreads();

    // tin = depth[n] + sum of sibp along chain (excl. root); scatter outputs
    {
        int t = d0, a = n0;
        while (a != 0) { t += P.sibp[a]; a = P.parL[a]; }
        P.tmpTok[t] = P.tokL[n0];
        P.tmpEnd[t] = (unsigned short)(n0 == 0 ? NPB - 1 : t + P.sizeL[n0] - 1);
    }
    if (n1 < NPB) {
        int t = d1, a = n1;
        while (a != 0) { t += P.sibp[a]; a = P.parL[a]; }
        P.tmpTok[t] = P.tokL[n1];
        P.tmpEnd[t] = (unsigned short)(t + P.sizeL[n1] - 1);
    }
    __syncthreads();

    for (int t = tid; t < NPB; t += 256) {
        tokD[base + t] = P.tmpTok[t];
        endD[base + t] = P.tmpEnd[t];
    }
}

// ---------------- fused gather + prefix-scan + subtree-max ----------------
// ONE BLOCK PER BATCH (all 128 channels): grid 512 x 1024 thr, LDS 137 KB
// (gfx950 allows >64 KB static; 73 KB precedent R2-R6). Occupancy unchanged
// (16 waves/CU, VGPR-capped) but serial round count 4 -> 2: halves per-round
// fixed costs (gather ramp, barrier drains, launch tail) and tokD/endD
// traffic; partials loop 31 -> 15 iters; 2x in-flight DMA per block.
// Channel-PAIRED as in R6: thread owns channels (2jp, 2jp+1), every LDS
// access is b32. Bank audit: dword idx = t*64 + jp -> 2-way alias (free);
// extract row wave-uniform. DMA dest = wave base + 16*lane (m104 linear).
// NO forced min-waves (R3: forcing spills x[] -> +12.5 us).
__global__ __launch_bounds__(1024) void scan_k(const int* __restrict__ tokD,
                                               const unsigned short* __restrict__ endD,
                                               const unsigned short* __restrict__ Eb,
                                               float* __restrict__ out) {
    const int b = blockIdx.x, tid = threadIdx.x;
    const long long base = (long long)b * NPB;
    __shared__ unsigned short Sbf[NPB * 128];  // 128000 B: values, then prefix (bf16)
    __shared__ unsigned short endL[NPB];       // 1000 B
    __shared__ float2 pw[16 * 64];             // 8192 B: partials, then wmax

    // DMA gather: node n = (tid>>4)+u*64, chunk q = tid&15 (16 lanes = 256 B/row).
    #pragma unroll
    for (int u = 0; u < 8; ++u) {
        int n = (tid >> 4) + u * 64;
        if (n < NPB) {
            int tok = tokD[base + n];          // 16 consecutive lanes share one int
            const unsigned short* g = &Eb[(long long)tok * DIM + (tid & 15) * 8];
            __builtin_amdgcn_global_load_lds(
                (const __attribute__((address_space(1))) void*)g,
                (__attribute__((address_space(3))) void*)&Sbf[n * 128 + (tid & 15) * 8],
                16, 0, 0);
        }
    }
    // overlap with DMA flight
    if (tid < NPB) endL[tid] = endD[base + tid];
    __syncthreads();

    const int jp = tid & 63;      // channel pair: channels 2jp, 2jp+1
    const int c  = tid >> 6;      // chunk 0..15, 32 nodes each (15 has tail)
    float x0[32], x1[32];
    {   // consume own chunk: one b32 read = both channels' bf16 values
        float run0 = 0.f, run1 = 0.f;
        #pragma unroll
        for (int k = 0; k < 32; ++k) {
            int t = c * 32 + k;
            unsigned v = (t < NPB) ? *(const unsigned*)&Sbf[t * 128 + jp * 2] : 0u;
            run0 += __uint_as_float(v << 16);
            run1 += __uint_as_float(v & 0xffff0000u);
            x0[k] = run0; x1[k] = run1;
        }
        pw[c * 64 + jp] = (float2){run0, run1};
    }
    __syncthreads();
    float off0 = 0.f, off1 = 0.f;
    for (int cc = 0; cc < c; ++cc) {
        float2 p = pw[cc * 64 + jp];
        off0 += p.x; off1 += p.y;
    }
    #pragma unroll
    for (int k = 0; k < 32; ++k) {   // write back packed bf16 prefix to OWN slots
        int t = c * 32 + k;
        x0[k] += off0; x1[k] += off1;
        if (t < NPB) {
            unsigned pk = ((unsigned)f2bf(x1[k]) << 16) | (unsigned)f2bf(x0[k]);
            *(unsigned*)&Sbf[t * 128 + jp * 2] = pk;
        }
    }
    __syncthreads();   // also: all pw(partials) reads are done -> reuse as wmax

    // extract: lo from registers (full f32), hi from packed bf16 prefix
    float m0 = -INFINITY, m1 = -INFINITY;
    #pragma unroll
    for (int k = 0; k < 32; ++k) {
        int t = c * 32 + k;
        if (t < NPB) {
            unsigned pk = *(const unsigned*)&Sbf[(int)endL[t] * 128 + jp * 2];
            float hi0 = __uint_as_float(pk << 16);
            float hi1 = __uint_as_float(pk & 0xffff0000u);
            float lo0 = (k > 0) ? x0[k - 1] : off0;
            float lo1 = (k > 0) ? x1[k - 1] : off1;
            m0 = fmaxf(m0, hi0 - lo0);
            m1 = fmaxf(m1, hi1 - lo1);
        }
    }
    pw[c * 64 + jp] = (float2){m0, m1};        // wave-uniform c: no shfl needed
    __syncthreads();
    if (tid < 64) {
        float2 mm = pw[tid];
        #pragma unroll
        for (int w = 1; w < 16; ++w) {
            float2 p = pw[w * 64 + tid];
            mm.x = fmaxf(mm.x, p.x);
            mm.y = fmaxf(mm.y, p.y);
        }
        float2 o = (float2){fmaxf(mm.x, 0.0f), fmaxf(mm.y, 0.0f)};
        *(float2*)&out[b * DIM + 2 * tid] = o;
    }
}

extern "C" void kernel_launch(void* const* d_in, const int* in_sizes, int n_in,
                              void* d_out, int out_size, void* d_ws, size_t ws_size,
                              hipStream_t stream) {
    const int*   tokens = (const int*)d_in[0];
    const int*   parent = (const int*)d_in[1];
    const int*   depth  = (const int*)d_in[2];
    // d_in[3] = node2batch (unused: node2batch[n] == n / 500 by construction)
    const float* emb    = (const float*)d_in[4];
    const float* Wc     = (const float*)d_in[5];
    const float* bc     = (const float*)d_in[6];
    float*       out    = (float*)d_out;

    unsigned short* Eb   = (unsigned short*)d_ws;                   // 12.8 MB bf16
    int*            tokD = (int*)(Eb + (long long)VOCAB * DIM);     // 1 MB
    unsigned short* endD = (unsigned short*)(tokD + B_BATCH * NPB); // 0.5 MB

    prep_gemm<<<NPREP + NGEMM, 256, 0, stream>>>(tokens, parent, depth,
                                                 emb, Wc, bc, tokD, endD, Eb);
    scan_k<<<B_BATCH, 1024, 0, stream>>>(tokD, endD, Eb, out);
}